// Round 6
// baseline (597.653 us; speedup 1.0000x reference)
//
#include <hip/hip_runtime.h>
#include <hip/hip_bf16.h>

// Problem constants
#define PDIM 4096
#define BDIM 32
#define MDIM (PDIM*BDIM)   // 131072 rows of x
#define KDIM 512           // FEAT
#define NDIM 512           // ATTN
#define NH   8
#define HD   64

typedef __attribute__((ext_vector_type(4))) float f32x4;
typedef __attribute__((ext_vector_type(8))) short bf16x8;

__device__ __forceinline__ unsigned short f2bf(float f) {
  unsigned u = __float_as_uint(f);
  u += 0x7fffu + ((u >> 16) & 1u);
  return (unsigned short)(u >> 16);
}
__device__ __forceinline__ float bf2f(unsigned short u) {
  return __uint_as_float(((unsigned)u) << 16);
}

// fast tanh via exp; abs error ~1e-7, arg clamped so no overflow
__device__ __forceinline__ float fast_tanh(float x) {
  x = fminf(fmaxf(x, -15.f), 15.f);
  float e = __expf(2.f * x);
  return __fdividef(e - 1.f, e + 1.f);
}

// async global->LDS 16B DMA (lane-linear LDS layout, no padding)
#define GLOAD_LDS16(g, l) __builtin_amdgcn_global_load_lds( \
    (const __attribute__((address_space(1))) void*)(g),     \
    (__attribute__((address_space(3))) void*)(l), 16, 0, 0)

// ---------------- fused prep: wft (blocks 0..511) + hub (512..543) ----------
// wft: WfT[n,k] = sum_kk Wa[k, h*64+kk] * Wa2[kk, j]  (bf16, N-major)
// hub: hid[b,a] = lh[b]@Ua + Ua_b;
//      ubf[b,n] = hid@Ua2 + Ua2_b + Wa_b@Wa2 + Wa2_b
__global__ __launch_bounds__(512) void prep_k(
    const float* __restrict__ Wa, const float* __restrict__ Wa2,
    unsigned short* __restrict__ WfT,
    const float* __restrict__ lh, const float* __restrict__ Ua,
    const float* __restrict__ Ua_b, const float* __restrict__ Ua2,
    const float* __restrict__ Ua2_b, const float* __restrict__ Wa_b,
    const float* __restrict__ Wa2_b, float* __restrict__ ubf) {
  int tid = threadIdx.x;
  if (blockIdx.x < 512) {
    int n = blockIdx.x;
    int h = n >> 6, j = n & 63;
    __shared__ float w2[64];
    if (tid < 64) w2[tid] = Wa2[tid*64 + j];
    __syncthreads();
    int k = tid;           // 512 threads, one k each
    float s = 0.f;
    #pragma unroll 8
    for (int kk = 0; kk < 64; ++kk)
      s += Wa[(size_t)k*512 + h*64 + kk] * w2[kk];
    WfT[(size_t)n*512 + k] = f2bf(s);
  } else {
    int b = blockIdx.x - 512;
    __shared__ float ls[512];
    __shared__ float hs[512];
    ls[tid] = lh[b*512 + tid];
    __syncthreads();
    float s = Ua_b[tid];
    #pragma unroll 8
    for (int k = 0; k < 512; ++k)
      s += ls[k] * Ua[(size_t)k*512 + tid];
    hs[tid] = s;
    __syncthreads();
    int h = tid >> 6, j = tid & 63;
    float u = Ua2_b[j] + Wa2_b[j];
    #pragma unroll 4
    for (int k = 0; k < 64; ++k) {
      u += hs[h*64 + k] * Ua2[k*64 + j];
      u += Wa_b[h*64 + k] * Wa2[k*64 + j];
    }
    ubf[b*512 + tid] = u;
  }
}

// ---------------- main GEMM + cvt fusion + score epilogue ----------------
// C[m,n] = x[m,:] @ Wf[:,n]; score[h,b,p] = va_b + sum_j tanh(C+ubf)*va[j]
// R4 structure (32 KB LDS, 2 barriers/K-step, 4+ blocks/CU, XCD swizzle,
// k-fastest 16-line staging) with the fp32->bf16 conversion FOLDED IN:
//  - A: reg-staged from x fp32 (8x dwordx4/thread/K-step, 8 rows x 256 B
//    contiguous = 16 lines/instr), f2bf (RTNE, same as old cvt_k), then
//    ds_write_b128 into XOR-swizzled slot (dest-side swizzle; read side
//    unchanged -> same involution as R4).
//  - bn==0 sibling also stores the bf16 tile to xbf for ctx_partial
//    (coalesced 16 B chunks); gemm had ~95% spare HBM bandwidth.
//  - B: unchanged gload_lds DMA with source-side XOR swizzle.
// This deletes the standalone cvt pass (768 MB of pure-BW traffic).
__global__ __launch_bounds__(256, 4) void gemm_score_k(
    const float* __restrict__ x, unsigned short* __restrict__ xbf,
    const unsigned short* __restrict__ WfT,
    const float* __restrict__ ubf, const float* __restrict__ va_w,
    const float* __restrict__ va_b, float* __restrict__ scores) {
  __shared__ __align__(16) unsigned short sm[16384];   // 32 KB total
  unsigned short* As = sm;          // 16 KB: [row 0..127][slot 0..7] 16B chunks
  unsigned short* Bs = sm + 8192;   // 16 KB
  int tid = threadIdx.x;
  // bijective XCD swizzle (4096 % 8 == 0): 4 bn-siblings adjacent on one XCD
  int orig = blockIdx.x;
  int wg = (orig & 7) * 512 + (orig >> 3);
  int bn = wg & 3, bm = wg >> 2;
  int m0 = bm*128, n0 = bn*128;
  int lane = tid & 63, w = tid >> 6;
  int quad = lane >> 4, l16 = lane & 15;
  int wr = w >> 1, wc = w & 1;
  int xr = (l16 & 7) << 4;          // read-side XOR (bits 4-6 of byte addr)
  f32x4 acc[4][4] = {};

  for (int k0 = 0; k0 < KDIM; k0 += 64) {
    __syncthreads();
    // B: 1024 chunks of 16B; chunk c -> row=c>>3, slot=c&7 (k-fastest);
    // source kc XOR-permuted within the row's 128 B (stays coalesced)
    #pragma unroll
    for (int i = 0; i < 4; ++i) {
      int c = i*256 + tid;
      int r = c >> 3, kc = (c & 7) ^ (r & 7);
      GLOAD_LDS16(WfT + (size_t)(n0 + r)*512 + k0 + kc*8, Bs + (size_t)c*8);
    }
    // A: reg-stage fp32, convert, ds_write swizzled; bn==0 writes xbf
    #pragma unroll
    for (int half = 0; half < 2; ++half) {
      float4 av[2][2];
      #pragma unroll
      for (int i = 0; i < 2; ++i) {
        int p = (half*2 + i)*256 + tid;
        int r = p >> 3, c8 = p & 7;
        const float4* s = (const float4*)(x + (size_t)(m0 + r)*512 + k0 + c8*8);
        av[i][0] = s[0]; av[i][1] = s[1];
      }
      #pragma unroll
      for (int i = 0; i < 2; ++i) {
        int p = (half*2 + i)*256 + tid;
        int r = p >> 3, c8 = p & 7;
        bf16x8 v;
        v[0] = (short)f2bf(av[i][0].x); v[1] = (short)f2bf(av[i][0].y);
        v[2] = (short)f2bf(av[i][0].z); v[3] = (short)f2bf(av[i][0].w);
        v[4] = (short)f2bf(av[i][1].x); v[5] = (short)f2bf(av[i][1].y);
        v[6] = (short)f2bf(av[i][1].z); v[7] = (short)f2bf(av[i][1].w);
        if (bn == 0)
          *(bf16x8*)(xbf + (size_t)(m0 + r)*512 + k0 + c8*8) = v;
        int slot = c8 ^ (r & 7);
        *(bf16x8*)(As + (size_t)(r*8 + slot)*8) = v;
      }
    }
    __syncthreads();   // drains vmcnt (B DMA) + lgkmcnt (A ds_writes)
    #pragma unroll
    for (int kk = 0; kk < 64; kk += 32) {
      int kc = (kk >> 3) + quad;
      bf16x8 af[4], bfr[4];
      #pragma unroll
      for (int ti = 0; ti < 4; ++ti) {
        int row = 64*wr + 16*ti + l16;
        af[ti] = *(const bf16x8*)((const char*)As + ((row*128 + kc*16) ^ xr));
      }
      #pragma unroll
      for (int tj = 0; tj < 4; ++tj) {
        int row = 64*wc + 16*tj + l16;
        bfr[tj] = *(const bf16x8*)((const char*)Bs + ((row*128 + kc*16) ^ xr));
      }
      #pragma unroll
      for (int ti = 0; ti < 4; ++ti)
        #pragma unroll
        for (int tj = 0; tj < 4; ++tj)
          acc[ti][tj] = __builtin_amdgcn_mfma_f32_16x16x32_bf16(
              af[ti], bfr[tj], acc[ti][tj], 0, 0, 0);
    }
  }

  // epilogue: stage ubf tile into the freed A/B buffer (stride 129 pad)
  __syncthreads();                    // all waves done reading As/Bs
  float* ubf_s = (float*)sm;          // 32*129*4 = 16.5 KB < 32 KB
  #pragma unroll
  for (int t = 0; t < 16; ++t) {
    int idx = t*256 + tid;
    int b = idx >> 7, c = idx & 127;
    ubf_s[b*129 + c] = ubf[b*512 + n0 + c];
  }
  __syncthreads();

  int head = bn*2 + wc;
  float va_r[4];
  #pragma unroll
  for (int tj = 0; tj < 4; ++tj) va_r[tj] = va_w[16*tj + l16];
  float vb = va_b[0];
  #pragma unroll
  for (int ti = 0; ti < 4; ++ti) {
    #pragma unroll
    for (int r = 0; r < 4; ++r) {
      int row_loc = 64*wr + 16*ti + 4*quad + r;   // C/D layout: row=quad*4+reg
      int b31 = row_loc & 31;                     // batch index = row % 32
      float s = 0.f;
      #pragma unroll
      for (int tj = 0; tj < 4; ++tj) {
        float xa = acc[ti][tj][r] + ubf_s[b31*129 + 64*wc + 16*tj + l16];
        s += fast_tanh(xa) * va_r[tj];
      }
      s += __shfl_xor(s, 1); s += __shfl_xor(s, 2);
      s += __shfl_xor(s, 4); s += __shfl_xor(s, 8);
      if (l16 == 0) {
        int m = m0 + row_loc;
        // transposed layout [h][b][p] -> coalesced softmax / ctx / mean reads
        scores[((size_t)head*32 + (m & 31))*4096 + (m >> 5)] = s + vb;
      }
    }
  }
}

// ---------------- softmax over P per (b,h) ----------------
// scores layout [h*32+b][p]: fully coalesced float4 reads/writes.
__global__ __launch_bounds__(256) void softmax_k(
    const float* __restrict__ sc, float* __restrict__ w) {
  int bh = blockIdx.x;                 // h*32 + b
  int tid = threadIdx.x;
  const float* row = sc + (size_t)bh*4096;
  float4 v[4];
  float mx = -1e30f;
  #pragma unroll
  for (int i = 0; i < 4; ++i) {
    v[i] = *(const float4*)(row + (size_t)(i*256 + tid)*4);
    mx = fmaxf(mx, fmaxf(fmaxf(v[i].x, v[i].y), fmaxf(v[i].z, v[i].w)));
  }
  #pragma unroll
  for (int m = 1; m < 64; m <<= 1) mx = fmaxf(mx, __shfl_xor(mx, m));
  __shared__ float redm[4], reds[4];
  int wid = tid >> 6, lane = tid & 63;
  if (lane == 0) redm[wid] = mx;
  __syncthreads();
  mx = fmaxf(fmaxf(redm[0], redm[1]), fmaxf(redm[2], redm[3]));
  float sum = 0.f;
  #pragma unroll
  for (int i = 0; i < 4; ++i) {
    v[i].x = __expf(v[i].x - mx); v[i].y = __expf(v[i].y - mx);
    v[i].z = __expf(v[i].z - mx); v[i].w = __expf(v[i].w - mx);
    sum += v[i].x + v[i].y + v[i].z + v[i].w;
  }
  #pragma unroll
  for (int m = 1; m < 64; m <<= 1) sum += __shfl_xor(sum, m);
  if (lane == 0) reds[wid] = sum;
  __syncthreads();
  sum = reds[0] + reds[1] + reds[2] + reds[3];
  float inv = 1.f / sum;
  float* dst = w + (size_t)bh*4096;
  #pragma unroll
  for (int i = 0; i < 4; ++i) {
    float4 o; o.x = v[i].x*inv; o.y = v[i].y*inv; o.z = v[i].z*inv; o.w = v[i].w*inv;
    *(float4*)(dst + (size_t)(i*256 + tid)*4) = o;
  }
}

// weight output = mean over heads; w[h*32+b][p] -> out[P*32+b] (p*32+b)
// per block: p-chunk of 256 x all (h,b): coalesced reads, coalesced 128B writes
__global__ __launch_bounds__(256) void mean_k(
    const float* __restrict__ w, float* __restrict__ out) {
  int p0 = blockIdx.x * 256;
  int tid = threadIdx.x;
  float s[32];
  #pragma unroll
  for (int b = 0; b < 32; ++b) s[b] = 0.f;
  for (int h = 0; h < 8; ++h) {
    #pragma unroll
    for (int b = 0; b < 32; ++b)
      s[b] += w[((size_t)h*32 + b)*4096 + p0 + tid];
  }
  float4* dst = (float4*)(out + BDIM*NDIM + (size_t)(p0 + tid)*32);
  #pragma unroll
  for (int j = 0; j < 8; ++j) {
    float4 o;
    o.x = s[4*j]*0.125f; o.y = s[4*j+1]*0.125f;
    o.z = s[4*j+2]*0.125f; o.w = s[4*j+3]*0.125f;
    dst[j] = o;
  }
}

// ---------------- context: cx[b,h,f] = sum_p w[h,b,p]*x[p,b,f] ----------------
// bf16 x (written by gemm, L3-warm), per-wave accumulate 64 p-rows, LDS reduce.
__global__ __launch_bounds__(256) void ctx_partial_k(
    const unsigned short* __restrict__ xbf, const float* __restrict__ w,
    float* __restrict__ part) {
  int pc = blockIdx.x;   // 16 chunks of 256 pixels
  int b  = blockIdx.y;   // 32 batches
  int tid = threadIdx.x;
  __shared__ float wl[8*256];     // [h][p_local]
  __shared__ float red[4][512];
  #pragma unroll
  for (int h = 0; h < 8; ++h)
    wl[h*256 + tid] = w[((size_t)h*32 + b)*4096 + pc*256 + tid];  // coalesced
  __syncthreads();
  int lane = tid & 63, wv = tid >> 6;
  float acc[8][8];
  #pragma unroll
  for (int h = 0; h < 8; ++h)
    #pragma unroll
    for (int j = 0; j < 8; ++j) acc[h][j] = 0.f;
  for (int i = 0; i < 64; ++i) {
    int pl = wv*64 + i;
    bf16x8 xv = *(const bf16x8*)(xbf + ((size_t)((pc*256 + pl)*32 + b))*512 + lane*8);
    float xf[8];
    #pragma unroll
    for (int j = 0; j < 8; ++j) xf[j] = bf2f((unsigned short)xv[j]);
    #pragma unroll
    for (int h = 0; h < 8; ++h) {
      float ww = wl[h*256 + pl];    // wave-uniform -> LDS broadcast
      #pragma unroll
      for (int j = 0; j < 8; ++j) acc[h][j] += ww * xf[j];
    }
  }
  // cross-wave reduce per head, write part[b][pc][h][f]
  for (int h = 0; h < 8; ++h) {
    #pragma unroll
    for (int j = 0; j < 8; j += 4)
      *(float4*)(&red[wv][lane*8 + j]) = *(float4*)(&acc[h][j]);
    __syncthreads();
    if (tid < 64) {
      #pragma unroll
      for (int j = 0; j < 8; ++j) {
        int f = tid*8 + j;
        part[((size_t)(b*16 + pc)*NH + h)*512 + f] =
            red[0][f] + red[1][f] + red[2][f] + red[3][f];
      }
    }
    __syncthreads();
  }
}

// fused ctx reduce + projection: block = (b*8+h)
// cx[b,h,f] = sum_pc part[b][pc][h][f];  out[b, h*64+d] = Wa_b + cx @ Wa
__global__ __launch_bounds__(256) void ctx_rp_k(
    const float* __restrict__ part, const float* __restrict__ Wa,
    const float* __restrict__ Wa_b, float* __restrict__ out) {
  int bh = blockIdx.x;                // b*8 + h
  int b = bh >> 3, h = bh & 7;
  int tid = threadIdx.x;
  __shared__ float cs[512];
  float s0 = 0.f, s1 = 0.f;
  #pragma unroll
  for (int pc = 0; pc < 16; ++pc) {
    const float* p = part + ((size_t)(b*16 + pc)*NH + h)*512;
    s0 += p[tid];
    s1 += p[tid + 256];
  }
  cs[tid] = s0; cs[tid + 256] = s1;
  __syncthreads();
  int d = tid & 63, g = tid >> 6;
  float s = 0.f;
  #pragma unroll 8
  for (int f = g*128; f < g*128 + 128; ++f)
    s += cs[f] * Wa[(size_t)f*512 + h*64 + d];
  __shared__ float red[256];
  red[tid] = s;
  __syncthreads();
  if (tid < 64) {
    float tot = red[tid] + red[64+tid] + red[128+tid] + red[192+tid] + Wa_b[h*64 + tid];
    out[b*512 + h*64 + tid] = tot;
  }
}

extern "C" void kernel_launch(void* const* d_in, const int* in_sizes, int n_in,
                              void* d_out, int out_size, void* d_ws, size_t ws_size,
                              hipStream_t stream) {
  (void)in_sizes; (void)n_in; (void)out_size; (void)ws_size;
  const float* lh    = (const float*)d_in[0];
  const float* x     = (const float*)d_in[1];
  const float* Wa_w  = (const float*)d_in[2];
  const float* Wa_b  = (const float*)d_in[3];
  const float* Ua_w  = (const float*)d_in[4];
  const float* Ua_b  = (const float*)d_in[5];
  const float* Wa2_w = (const float*)d_in[6];
  const float* Wa2_b = (const float*)d_in[7];
  const float* Ua2_w = (const float*)d_in[8];
  const float* Ua2_b = (const float*)d_in[9];
  const float* va_w  = (const float*)d_in[10];
  const float* va_b  = (const float*)d_in[11];
  float* out = (float*)d_out;
  char* ws = (char*)d_ws;

  unsigned short* xbf = (unsigned short*)(ws);            // 134,217,728 B
  unsigned short* WfT = (unsigned short*)(ws + 134217728);// 524,288 B
  float* ubf    = (float*)(ws + 134742016);               // 65,536 B
  float* scores = (float*)(ws + 134807552);               // 4,194,304 B  [h][b][p]
  float* w      = (float*)(ws + 139001856);               // 4,194,304 B  [h][b][p]
  float* part   = (float*)(ws + 143196160);               // 8,388,608 B
  float* cx     = (float*)(ws + 151584768);               // 65,536 B (unused now)
  (void)cx;

  hipLaunchKernelGGL(prep_k, dim3(544), dim3(512), 0, stream,
                     Wa_w, Wa2_w, WfT,
                     lh, Ua_w, Ua_b, Ua2_w, Ua2_b, Wa_b, Wa2_b, ubf);
  hipLaunchKernelGGL(gemm_score_k, dim3(4096), dim3(256), 0, stream,
                     x, xbf, WfT, ubf, va_w, va_b, scores);
  hipLaunchKernelGGL(softmax_k, dim3(256), dim3(256), 0, stream, scores, w);
  hipLaunchKernelGGL(mean_k, dim3(16), dim3(256), 0, stream, w, out);
  hipLaunchKernelGGL(ctx_partial_k, dim3(16, 32), dim3(256), 0, stream, xbf, w, part);
  hipLaunchKernelGGL(ctx_rp_k, dim3(256), dim3(256), 0, stream, part, Wa_w, Wa_b, out);
}